// Round 12
// baseline (85.486 us; speedup 1.0000x reference)
//
#include <hip/hip_runtime.h>
#include <hip/hip_bf16.h>
#include <stdint.h>

#define N_ROWS 50000
#define D 384
#define K 8
#define BATCH 512
#define NEGO 128
#define NEDGE 1024
#define EPS_G 1e-4f

typedef float f32x4 __attribute__((ext_vector_type(4)));
typedef short bf16x8 __attribute__((ext_vector_type(8)));
typedef unsigned short ushort8v __attribute__((ext_vector_type(8)));

__device__ __forceinline__ float wave_reduce_sum(float v) {
#pragma unroll
    for (int d = 1; d < 64; d <<= 1) v += __shfl_xor(v, d);
    return v;
}

static __device__ __forceinline__ uint16_t f2bfbits(float f) {
    __hip_bfloat16 h = __float2bfloat16(f);
    union { __hip_bfloat16 h; uint16_t u; } cv;
    cv.h = h;
    return cv.u;
}

// ---------------------------------------------------------------------------
// Kernel A: normalize virtual rows; G = Vn Vn^T + eps I; Ginv (8x8 GJ);
// M1 = Ginv + eps*Ginv^2; Vbf = bf16 Vn padded to 16 rows (rows 8..15 = 0).
// Fusion identity: (I-P)^2 = I - P - eps*V^T Ginv^2 V  (V V^T = G - eps I)
//   => R R^T = X X^T - (X V^T) M1 (X V^T)^T  exactly.
// ---------------------------------------------------------------------------
__global__ __launch_bounds__(64) void prep_kernel(const float* __restrict__ virt,
                                                  float* __restrict__ Vn,
                                                  float* __restrict__ Ginv,
                                                  float* __restrict__ M1,
                                                  uint16_t* __restrict__ Vbf) {
    __shared__ float Vs[K * D];
    __shared__ float Gs[K * K];
    int tid = threadIdx.x;
    for (int t = tid; t < K * D; t += 64) Vs[t] = virt[t];
    __syncthreads();
    for (int k = 0; k < K; ++k) {
        float ss = 0.f;
        for (int t = tid; t < D; t += 64) { float v = Vs[k * D + t]; ss += v * v; }
        ss = wave_reduce_sum(ss);
        float inv = 1.0f / sqrtf(ss + 1e-12f);
        for (int t = tid; t < D; t += 64) {
            float v = Vs[k * D + t] * inv;
            Vs[k * D + t] = v;
            Vn[k * D + t] = v;
        }
        __syncthreads();
    }
    int k = tid >> 3, m = tid & 7;
    float g = 0.f;
    for (int j = 0; j < D; ++j) g += Vs[k * D + j] * Vs[m * D + j];
    if (k == m) g += EPS_G;
    Gs[tid] = g;
    __syncthreads();
    if (tid == 0) {
        float A[K][K], I8[K][K];
        for (int a = 0; a < K; ++a)
            for (int b2 = 0; b2 < K; ++b2) {
                A[a][b2] = Gs[a * K + b2];
                I8[a][b2] = (a == b2) ? 1.f : 0.f;
            }
        for (int p = 0; p < K; ++p) {
            float piv = 1.0f / A[p][p];
            for (int j = 0; j < K; ++j) { A[p][j] *= piv; I8[p][j] *= piv; }
            for (int r = 0; r < K; ++r)
                if (r != p) {
                    float f = A[r][p];
                    for (int j = 0; j < K; ++j) {
                        A[r][j] -= f * A[p][j];
                        I8[r][j] -= f * I8[p][j];
                    }
                }
        }
        for (int a = 0; a < K; ++a)
            for (int b2 = 0; b2 < K; ++b2) {
                Ginv[a * K + b2] = I8[a][b2];
                float q = 0.f;
                for (int c = 0; c < K; ++c) q += I8[a][c] * I8[c][b2];
                M1[a * K + b2] = I8[a][b2] + EPS_G * q;
            }
    }
    // Vbf: bf16 normalized V, [16][384], rows 8..15 zero (no div/mod)
#pragma unroll
    for (int r = 0; r < 16; ++r)
        for (int cj = tid; cj < D; cj += 64)
            Vbf[r * D + cj] = (r < K) ? f2bfbits(Vs[r * D + cj]) : (uint16_t)0;
}

// ---------------------------------------------------------------------------
// Kernel C (fused, MFMA): per ego-graph from RAW emb rows.
// R11 post-mortem: 114.7KB LDS -> 1 block/CU -> barrier-serialized phases
// with zero cross-block overlap (occupancy 20%, nothing saturated).
// R12: stage D in 4 QUARTERS of 96 cols. Xs = 128 x 256B (padded, pow-2
// stride so the ^(row&7)<<4 swizzle stays in-row) = 32KB; total LDS ~49KB
// -> 2 blocks/CU; acc/accY accumulate across quarters in registers.
// Per quarter: 6 indep f32x4 loads/thread -> 3 x 16B swizzled ds_write,
// then 3 MFMA k-steps. gumbel+adjacency issued before the loop.
// ---------------------------------------------------------------------------
__global__ __launch_bounds__(512) void batch_kernel(const float* __restrict__ emb,
                                                    const float* __restrict__ gumbel,
                                                    const int* __restrict__ idx_batch,
                                                    const int* __restrict__ edges_src,
                                                    const int* __restrict__ edges_dst,
                                                    const __hip_bfloat16* __restrict__ Vbf,
                                                    const float* __restrict__ M1,
                                                    float* __restrict__ scores) {
    __shared__ __hip_bfloat16 Xs[NEGO * 128];  // 32768 B: row stride 256B, one 96-col quarter
    __shared__ uint32_t adjmask[NEGO * 4];     // 2048 B
    __shared__ int idxs[NEGO];
    __shared__ float Yl[NEGO][12];             // Y (cols 0..7 used)
    __shared__ float Al[NEGO][12];             // A = Y*M1
    __shared__ float diagL[NEGO];
    __shared__ float invrL[NEGO];
    __shared__ float red[8];
    int tid = threadIdx.x;
    int b = blockIdx.x;
    if (tid < NEGO) idxs[tid] = idx_batch[b * NEGO + tid];
    adjmask[tid] = 0u;
    __syncthreads();

    int w = tid >> 6, l = tid & 63;
    int c15 = l & 15, g4 = l >> 4;

    // ---- adjacency bitmask (completes well before softmax) ----
    for (int e = tid; e < NEDGE; e += 512) {
        int s = edges_src[b * NEDGE + e];
        int dd = edges_dst[b * NEDGE + e];
        atomicOr(&adjmask[s * 4 + (dd >> 5)], 1u << (dd & 31));
    }
    // ---- gumbel prefetch: overlaps the whole stage/MFMA pipeline ----
    float gpre[4][8];
    {
        const float* gb = gumbel + (size_t)b * NEGO * NEGO;
#pragma unroll
        for (int reg = 0; reg < 4; ++reg) {
            int row = w * 16 + g4 * 4 + reg;
#pragma unroll
            for (int t = 0; t < 8; ++t) gpre[reg][t] = gb[row * NEGO + 16 * t + c15];
        }
    }

    // ---- quartered stage + MFMA accumulate ----
    f32x4 acc[8];
    f32x4 accY = (f32x4){0.f, 0.f, 0.f, 0.f};
#pragma unroll
    for (int t = 0; t < 8; ++t) acc[t] = (f32x4){0.f, 0.f, 0.f, 0.f};
    const char* xb = (const char*)Xs;
    int ar = w * 16 + c15;
    int aswz = (ar & 7) << 4;
    int srow = tid >> 2, seg = tid & 3;

#pragma unroll
    for (int q = 0; q < 4; ++q) {
        if (q) __syncthreads();  // prior MFMA reads done before overwrite
        // stage quarter q: rows srow, f32x4 cols q*24 .. q*24+23
        {
            const f32x4* src = (const f32x4*)(emb + (size_t)idxs[srow] * D) + q * 24;
            f32x4 xa[6];
#pragma unroll
            for (int cc = 0; cc < 3; ++cc) {
                xa[2 * cc] = src[(seg * 3 + cc) * 2];
                xa[2 * cc + 1] = src[(seg * 3 + cc) * 2 + 1];
            }
            char* db = (char*)Xs;
#pragma unroll
            for (int cc = 0; cc < 3; ++cc) {
                int cj = seg * 3 + cc;
                ushort8v p;
                p[0] = f2bfbits(xa[2 * cc].x); p[1] = f2bfbits(xa[2 * cc].y);
                p[2] = f2bfbits(xa[2 * cc].z); p[3] = f2bfbits(xa[2 * cc].w);
                p[4] = f2bfbits(xa[2 * cc + 1].x); p[5] = f2bfbits(xa[2 * cc + 1].y);
                p[6] = f2bfbits(xa[2 * cc + 1].z); p[7] = f2bfbits(xa[2 * cc + 1].w);
                int off = (srow * 256 + cj * 16) ^ ((srow & 7) << 4);
                *(ushort8v*)(db + off) = p;
            }
        }
        __syncthreads();
        // 3 k-steps of this quarter
#pragma unroll
        for (int ks = 0; ks < 3; ++ks) {
            int kbyte = ks * 64 + g4 * 16;
            bf16x8 afrag = *(const bf16x8*)(xb + ((ar * 256 + kbyte) ^ aswz));
            bf16x8 vfrag = *(const bf16x8*)(Vbf + (size_t)c15 * D + q * 96 + ks * 32 + g4 * 8);
            accY = __builtin_amdgcn_mfma_f32_16x16x32_bf16(afrag, vfrag, accY, 0, 0, 0);
#pragma unroll
            for (int t = 0; t < 8; ++t) {
                int br = t * 16 + c15;
                bf16x8 bfrag = *(const bf16x8*)(xb + ((br * 256 + kbyte) ^ ((br & 7) << 4)));
                acc[t] = __builtin_amdgcn_mfma_f32_16x16x32_bf16(afrag, bfrag, acc[t], 0, 0, 0);
            }
        }
    }

    // ---- publish Y and the Gram diagonal ----
#pragma unroll
    for (int reg = 0; reg < 4; ++reg) {
        int row = w * 16 + g4 * 4 + reg;
        if (c15 < 8) Yl[row][c15] = accY[reg];
#pragma unroll
        for (int t = 0; t < 8; ++t)
            if (t == w && c15 == g4 * 4 + reg) diagL[row] = acc[t][reg];
    }
    __syncthreads();

    // ---- per-row rank-8 solve: A = Y M1, rss, invr ----
    if (tid < NEGO) {
        float y[K], a[K];
#pragma unroll
        for (int k = 0; k < K; ++k) y[k] = Yl[tid][k];
        float crr = 0.f;
#pragma unroll
        for (int k = 0; k < K; ++k) {
            float s = 0.f;
#pragma unroll
            for (int m = 0; m < K; ++m) s += y[m] * M1[m * K + k];
            a[k] = s;
            crr += s * y[k];
        }
#pragma unroll
        for (int k = 0; k < K; ++k) Al[tid][k] = a[k];
        invrL[tid] = 1.0f / sqrtf(diagL[tid] - crr + 1e-12f);
    }
    __syncthreads();

    // ---- fused normalize + gumbel softmax + adjacency diff + score ----
    float wave_score = 0.f;
#pragma unroll
    for (int reg = 0; reg < 4; ++reg) {
        int row = w * 16 + g4 * 4 + reg;
        const f32x4* ar4 = (const f32x4*)&Al[row][0];
        f32x4 a0 = ar4[0], a1 = ar4[1];
        float invr = invrL[row];
        float z[8];
#pragma unroll
        for (int t = 0; t < 8; ++t) {
            int col = 16 * t + c15;
            const f32x4* yc4 = (const f32x4*)&Yl[col][0];
            f32x4 y0 = yc4[0], y1 = yc4[1];
            float corr = a0.x * y0.x + a0.y * y0.y + a0.z * y0.z + a0.w * y0.w +
                         a1.x * y1.x + a1.y * y1.y + a1.z * y1.z + a1.w * y1.w;
            float s = (acc[t][reg] - corr) * invr * invrL[col];
            if (col == row) s = -1e9f;
            z[t] = s + gpre[reg][t];
        }
        float m = z[0];
#pragma unroll
        for (int t = 1; t < 8; ++t) m = fmaxf(m, z[t]);
#pragma unroll
        for (int d = 1; d < 16; d <<= 1) m = fmaxf(m, __shfl_xor(m, d));
        float e[8], se = 0.f;
#pragma unroll
        for (int t = 0; t < 8; ++t) { e[t] = expf(z[t] - m); se += e[t]; }
#pragma unroll
        for (int d = 1; d < 16; d <<= 1) se += __shfl_xor(se, d);
        float inv = 1.0f / se;
        uint32_t am[4];
#pragma unroll
        for (int qq = 0; qq < 4; ++qq) am[qq] = adjmask[row * 4 + qq];
        float sq = 0.f;
#pragma unroll
        for (int t = 0; t < 8; ++t) {
            int col = 16 * t + c15;
            float a = (float)((am[col >> 5] >> (col & 31)) & 1u);
            float d0 = a - e[t] * inv;
            sq += d0 * d0;
        }
#pragma unroll
        for (int d = 1; d < 16; d <<= 1) sq += __shfl_xor(sq, d);
        wave_score += sqrtf(sq);
    }
    wave_score += __shfl_xor(wave_score, 16);
    wave_score += __shfl_xor(wave_score, 32);
    if (l == 0) red[w] = wave_score;
    __syncthreads();
    if (tid == 0) {
        float tot = 0.f;
#pragma unroll
        for (int ww = 0; ww < 8; ++ww) tot += red[ww];
        scores[b] = tot * (1.0f / (float)NEGO);
    }
}

// ---------------------------------------------------------------------------
// Kernel D: min-max normalize scores, BCE loss.
// ---------------------------------------------------------------------------
__global__ __launch_bounds__(512) void finalize_kernel(const float* __restrict__ scores,
                                                       const int* __restrict__ labels,
                                                       float* __restrict__ out) {
    __shared__ float rmn[8], rmx[8], rsum[8];
    int tid = threadIdx.x, w = tid >> 6, l = tid & 63;
    float s = scores[tid];
    float mn = s, mx = s;
#pragma unroll
    for (int d = 1; d < 64; d <<= 1) {
        mn = fminf(mn, __shfl_xor(mn, d));
        mx = fmaxf(mx, __shfl_xor(mx, d));
    }
    if (l == 0) { rmn[w] = mn; rmx[w] = mx; }
    __syncthreads();
    mn = rmn[0]; mx = rmx[0];
#pragma unroll
    for (int ww = 1; ww < 8; ++ww) {
        mn = fminf(mn, rmn[ww]);
        mx = fmaxf(mx, rmx[ww]);
    }
    float norm = (s - mn) / (mx - mn + 1e-8f);
    out[tid] = norm;
    float y = (float)labels[tid];
    float lp = fmaxf(logf(norm), -100.0f);
    float l1p = fmaxf(log1pf(-norm), -100.0f);
    float term = y * lp + (1.0f - y) * l1p;
    term = wave_reduce_sum(term);
    if (l == 0) rsum[w] = term;
    __syncthreads();
    if (tid == 0) {
        float tot = 0.f;
        for (int ww = 0; ww < 8; ++ww) tot += rsum[ww];
        out[BATCH] = -tot / (float)BATCH;
    }
}

extern "C" void kernel_launch(void* const* d_in, const int* in_sizes, int n_in,
                              void* d_out, int out_size, void* d_ws, size_t ws_size,
                              hipStream_t stream) {
    (void)in_sizes; (void)n_in; (void)out_size; (void)ws_size;
    const float* text = (const float*)d_in[0];
    const float* virt = (const float*)d_in[1];
    const float* gum = (const float*)d_in[2];
    const int* idxb = (const int*)d_in[3];
    const int* esrc = (const int*)d_in[4];
    const int* edst = (const int*)d_in[5];
    const int* label = (const int*)d_in[6];
    float* out = (float*)d_out;

    float* Vn = (float*)d_ws;                 // 3072 f32
    float* Ginv = Vn + K * D;                 // 64 f32
    float* M1 = Ginv + K * K;                 // 64 f32
    float* scores = M1 + K * K;               // 512 f32
    uint16_t* Vbf = (uint16_t*)(scores + BATCH);  // 16*384 bf16 = 12288 B

    hipLaunchKernelGGL(prep_kernel, dim3(1), dim3(64), 0, stream, virt, Vn, Ginv, M1, Vbf);
    hipLaunchKernelGGL(batch_kernel, dim3(BATCH), dim3(512), 0, stream, text, gum, idxb,
                       esrc, edst, (const __hip_bfloat16*)Vbf, M1, scores);
    hipLaunchKernelGGL(finalize_kernel, dim3(1), dim3(512), 0, stream, scores, label, out);
}

// Round 13
// 63.032 us; speedup vs baseline: 1.3562x; 1.3562x over previous
//
#include <hip/hip_runtime.h>
#include <hip/hip_bf16.h>
#include <stdint.h>

#define N_ROWS 50000
#define D 384
#define K 8
#define BATCH 512
#define NEGO 128
#define NEDGE 1024
#define EPS_G 1e-4f

typedef float f32x4 __attribute__((ext_vector_type(4)));
typedef short bf16x8 __attribute__((ext_vector_type(8)));

__device__ __forceinline__ float wave_reduce_sum(float v) {
#pragma unroll
    for (int d = 1; d < 64; d <<= 1) v += __shfl_xor(v, d);
    return v;
}

static __device__ __forceinline__ uint16_t f2bfbits(float f) {
    __hip_bfloat16 h = __float2bfloat16(f);
    union { __hip_bfloat16 h; uint16_t u; } cv;
    cv.h = h;
    return cv.u;
}

// ---------------------------------------------------------------------------
// Kernel A (parallelized R13): normalize virtual rows; G = Vn Vn^T + eps I;
// Ginv by 64-thread Gauss-Jordan (thread = one (r,c) entry of the A|I pair);
// M1 = Ginv + eps*Ginv^2; Vbf = bf16 Vn padded to 16 rows.
// R12 post-mortem: the old serial tid==0 GJ+M1 (~2700 dependent scalar ops)
// gated every batch block. Single wave -> barriers are cheap.
// Fusion identity: (I-P)^2 = I - P - eps*V^T Ginv^2 V  (V V^T = G - eps I)
//   => R R^T = X X^T - (X V^T) M1 (X V^T)^T  exactly.
// ---------------------------------------------------------------------------
__global__ __launch_bounds__(64) void prep_kernel(const float* __restrict__ virt,
                                                  float* __restrict__ Vn,
                                                  float* __restrict__ Ginv,
                                                  float* __restrict__ M1,
                                                  uint16_t* __restrict__ Vbf) {
    __shared__ float Vs[K * D];
    __shared__ float As[K * K];   // working copy of G -> I
    __shared__ float Is[K * K];   // working copy of I -> Ginv
    int tid = threadIdx.x;
    for (int t = tid; t < K * D; t += 64) Vs[t] = virt[t];
    __syncthreads();
    for (int k = 0; k < K; ++k) {
        float ss = 0.f;
        for (int t = tid; t < D; t += 64) { float v = Vs[k * D + t]; ss += v * v; }
        ss = wave_reduce_sum(ss);
        float inv = 1.0f / sqrtf(ss + 1e-12f);
        for (int t = tid; t < D; t += 64) {
            float v = Vs[k * D + t] * inv;
            Vs[k * D + t] = v;
            Vn[k * D + t] = v;
        }
        __syncthreads();
    }
    // G via vectorized dot: thread (k,m)
    int k = tid >> 3, m = tid & 7;
    {
        const f32x4* a4 = (const f32x4*)&Vs[k * D];
        const f32x4* b4 = (const f32x4*)&Vs[m * D];
        float g = 0.f;
        for (int j = 0; j < 96; ++j) {
            f32x4 a = a4[j], b = b4[j];
            g += a.x * b.x + a.y * b.y + a.z * b.z + a.w * b.w;
        }
        if (k == m) g += EPS_G;
        As[tid] = g;
        Is[tid] = (k == m) ? 1.f : 0.f;
    }
    __syncthreads();
    // parallel Gauss-Jordan (no pivoting: G SPD, diag ~= 1+1e-4)
#pragma unroll
    for (int p = 0; p < K; ++p) {
        float piv = 1.0f / As[p * K + p];
        if (k == p) { As[tid] *= piv; Is[tid] *= piv; }
        __syncthreads();
        float f = As[k * K + p];
        float ap = As[p * K + m], ip = Is[p * K + m];
        __syncthreads();
        if (k != p) { As[tid] -= f * ap; Is[tid] -= f * ip; }
        __syncthreads();
    }
    // Ginv + M1 (thread (k,m))
    {
        float gi = Is[tid];
        Ginv[tid] = gi;
        float q = 0.f;
#pragma unroll
        for (int c = 0; c < K; ++c) q += Is[k * K + c] * Is[c * K + m];
        M1[tid] = gi + EPS_G * q;
    }
    // Vbf: bf16 normalized V, [16][384], rows 8..15 zero
#pragma unroll
    for (int r = 0; r < 16; ++r)
        for (int cj = tid; cj < D; cj += 64)
            Vbf[r * D + cj] = (r < K) ? f2bfbits(Vs[r * D + cj]) : (uint16_t)0;
}

// ---------------------------------------------------------------------------
// Kernel C (fused, MFMA) -- R11 structure (proven 52.8us; R12 quartering
// regressed by chopping the 24-deep staging load queue):
//  1. gather 128 rows x 384 f32 (24 indep loads/thread), cvt bf16, store
//     swizzled Xs (96KB LDS)
//  2. S = X X^T (96 MFMA) and Y = X Vbf^T (12 MFMA, shares afrag)
//  3. per row: A = Y M1, rss = S_rr - A.Y, invr = rsqrt
//  4. sim_ij = (S_ij - A_i.Y_j) invr_i invr_j -> diag mask, +gumbel,
//     softmax, adjacency-bitmask diff, score.
// ---------------------------------------------------------------------------
__global__ __launch_bounds__(512) void batch_kernel(const float* __restrict__ emb,
                                                    const float* __restrict__ gumbel,
                                                    const int* __restrict__ idx_batch,
                                                    const int* __restrict__ edges_src,
                                                    const int* __restrict__ edges_dst,
                                                    const __hip_bfloat16* __restrict__ Vbf,
                                                    const float* __restrict__ M1,
                                                    float* __restrict__ scores) {
    __shared__ __hip_bfloat16 Xs[NEGO * D];  // 98304 B, swizzled
    __shared__ uint32_t adjmask[NEGO * 4];   // 2048 B
    __shared__ int idxs[NEGO];
    __shared__ float Yl[NEGO][12];           // Y (cols 0..7 used)
    __shared__ float Al[NEGO][12];           // A = Y*M1
    __shared__ float diagL[NEGO];
    __shared__ float invrL[NEGO];
    __shared__ float red[8];
    int tid = threadIdx.x;
    int b = blockIdx.x;
    if (tid < NEGO) idxs[tid] = idx_batch[b * NEGO + tid];
    adjmask[tid] = 0u;
    __syncthreads();

    // ---- stage raw emb rows -> bf16 swizzled LDS (4 threads/row) ----
    {
        int row = tid >> 2, seg = tid & 3;
        const f32x4* src = (const f32x4*)(emb + (size_t)idxs[row] * D);
        f32x4 xt[24];
#pragma unroll
        for (int i = 0; i < 24; ++i) xt[i] = src[seg + 4 * i];
        char* db = (char*)Xs;
#pragma unroll
        for (int i = 0; i < 24; ++i) {
            int j = seg + 4 * i;  // f32x4 index within row (96 per row)
            ushort4 p;
            p.x = f2bfbits(xt[i].x); p.y = f2bfbits(xt[i].y);
            p.z = f2bfbits(xt[i].z); p.w = f2bfbits(xt[i].w);
            int off = (row * 768 + j * 8) ^ ((row & 7) << 4);
            *(ushort4*)(db + off) = p;
        }
    }
    // ---- adjacency bitmask ----
    for (int e = tid; e < NEDGE; e += 512) {
        int s = edges_src[b * NEDGE + e];
        int dd = edges_dst[b * NEDGE + e];
        atomicOr(&adjmask[s * 4 + (dd >> 5)], 1u << (dd & 31));
    }
    __syncthreads();

    int w = tid >> 6, l = tid & 63;
    int c15 = l & 15, g4 = l >> 4;

    // ---- gumbel prefetch: loads fly under the MFMA block ----
    float gpre[4][8];
    {
        const float* gb = gumbel + (size_t)b * NEGO * NEGO;
#pragma unroll
        for (int reg = 0; reg < 4; ++reg) {
            int row = w * 16 + g4 * 4 + reg;
#pragma unroll
            for (int t = 0; t < 8; ++t) gpre[reg][t] = gb[row * NEGO + 16 * t + c15];
        }
    }

    // ---- S = X X^T (8 tiles) and Y = X Vbf^T (shared afrag) ----
    f32x4 acc[8];
    f32x4 accY = (f32x4){0.f, 0.f, 0.f, 0.f};
#pragma unroll
    for (int t = 0; t < 8; ++t) acc[t] = (f32x4){0.f, 0.f, 0.f, 0.f};
    const char* xb = (const char*)Xs;
    int ar = w * 16 + c15;
    int aswz = (ar & 7) << 4;
    for (int ks = 0; ks < 12; ++ks) {
        int kbyte = ks * 64 + g4 * 16;
        bf16x8 afrag = *(const bf16x8*)(xb + ((ar * 768 + kbyte) ^ aswz));
        bf16x8 vfrag = *(const bf16x8*)(Vbf + (size_t)c15 * D + ks * 32 + g4 * 8);
        accY = __builtin_amdgcn_mfma_f32_16x16x32_bf16(afrag, vfrag, accY, 0, 0, 0);
#pragma unroll
        for (int t = 0; t < 8; ++t) {
            int br = t * 16 + c15;
            bf16x8 bfrag = *(const bf16x8*)(xb + ((br * 768 + kbyte) ^ ((br & 7) << 4)));
            acc[t] = __builtin_amdgcn_mfma_f32_16x16x32_bf16(afrag, bfrag, acc[t], 0, 0, 0);
        }
    }

    // ---- publish Y and the Gram diagonal ----
#pragma unroll
    for (int reg = 0; reg < 4; ++reg) {
        int row = w * 16 + g4 * 4 + reg;
        if (c15 < 8) Yl[row][c15] = accY[reg];
#pragma unroll
        for (int t = 0; t < 8; ++t)
            if (t == w && c15 == g4 * 4 + reg) diagL[row] = acc[t][reg];
    }
    __syncthreads();

    // ---- per-row rank-8 solve: A = Y M1, rss, invr ----
    if (tid < NEGO) {
        float y[K], a[K];
#pragma unroll
        for (int kk = 0; kk < K; ++kk) y[kk] = Yl[tid][kk];
        float crr = 0.f;
#pragma unroll
        for (int kk = 0; kk < K; ++kk) {
            float s = 0.f;
#pragma unroll
            for (int mm = 0; mm < K; ++mm) s += y[mm] * M1[mm * K + kk];
            a[kk] = s;
            crr += s * y[kk];
        }
#pragma unroll
        for (int kk = 0; kk < K; ++kk) Al[tid][kk] = a[kk];
        invrL[tid] = 1.0f / sqrtf(diagL[tid] - crr + 1e-12f);
    }
    __syncthreads();

    // ---- fused normalize + gumbel softmax + adjacency diff + score ----
    float wave_score = 0.f;
#pragma unroll
    for (int reg = 0; reg < 4; ++reg) {
        int row = w * 16 + g4 * 4 + reg;
        const f32x4* ar4 = (const f32x4*)&Al[row][0];
        f32x4 a0 = ar4[0], a1 = ar4[1];
        float invr = invrL[row];
        float z[8];
#pragma unroll
        for (int t = 0; t < 8; ++t) {
            int col = 16 * t + c15;
            const f32x4* yc4 = (const f32x4*)&Yl[col][0];
            f32x4 y0 = yc4[0], y1 = yc4[1];
            float corr = a0.x * y0.x + a0.y * y0.y + a0.z * y0.z + a0.w * y0.w +
                         a1.x * y1.x + a1.y * y1.y + a1.z * y1.z + a1.w * y1.w;
            float s = (acc[t][reg] - corr) * invr * invrL[col];
            if (col == row) s = -1e9f;
            z[t] = s + gpre[reg][t];
        }
        float m = z[0];
#pragma unroll
        for (int t = 1; t < 8; ++t) m = fmaxf(m, z[t]);
#pragma unroll
        for (int d = 1; d < 16; d <<= 1) m = fmaxf(m, __shfl_xor(m, d));
        float e[8], se = 0.f;
#pragma unroll
        for (int t = 0; t < 8; ++t) { e[t] = expf(z[t] - m); se += e[t]; }
#pragma unroll
        for (int d = 1; d < 16; d <<= 1) se += __shfl_xor(se, d);
        float inv = 1.0f / se;
        uint32_t am[4];
#pragma unroll
        for (int qq = 0; qq < 4; ++qq) am[qq] = adjmask[row * 4 + qq];
        float sq = 0.f;
#pragma unroll
        for (int t = 0; t < 8; ++t) {
            int col = 16 * t + c15;
            float a = (float)((am[col >> 5] >> (col & 31)) & 1u);
            float d0 = a - e[t] * inv;
            sq += d0 * d0;
        }
#pragma unroll
        for (int d = 1; d < 16; d <<= 1) sq += __shfl_xor(sq, d);
        wave_score += sqrtf(sq);
    }
    wave_score += __shfl_xor(wave_score, 16);
    wave_score += __shfl_xor(wave_score, 32);
    if (l == 0) red[w] = wave_score;
    __syncthreads();
    if (tid == 0) {
        float tot = 0.f;
#pragma unroll
        for (int ww = 0; ww < 8; ++ww) tot += red[ww];
        scores[b] = tot * (1.0f / (float)NEGO);
    }
}

// ---------------------------------------------------------------------------
// Kernel D: min-max normalize scores, BCE loss.
// ---------------------------------------------------------------------------
__global__ __launch_bounds__(512) void finalize_kernel(const float* __restrict__ scores,
                                                       const int* __restrict__ labels,
                                                       float* __restrict__ out) {
    __shared__ float rmn[8], rmx[8], rsum[8];
    int tid = threadIdx.x, w = tid >> 6, l = tid & 63;
    float s = scores[tid];
    float mn = s, mx = s;
#pragma unroll
    for (int d = 1; d < 64; d <<= 1) {
        mn = fminf(mn, __shfl_xor(mn, d));
        mx = fmaxf(mx, __shfl_xor(mx, d));
    }
    if (l == 0) { rmn[w] = mn; rmx[w] = mx; }
    __syncthreads();
    mn = rmn[0]; mx = rmx[0];
#pragma unroll
    for (int ww = 1; ww < 8; ++ww) {
        mn = fminf(mn, rmn[ww]);
        mx = fmaxf(mx, rmx[ww]);
    }
    float norm = (s - mn) / (mx - mn + 1e-8f);
    out[tid] = norm;
    float y = (float)labels[tid];
    float lp = fmaxf(logf(norm), -100.0f);
    float l1p = fmaxf(log1pf(-norm), -100.0f);
    float term = y * lp + (1.0f - y) * l1p;
    term = wave_reduce_sum(term);
    if (l == 0) rsum[w] = term;
    __syncthreads();
    if (tid == 0) {
        float tot = 0.f;
        for (int ww = 0; ww < 8; ++ww) tot += rsum[ww];
        out[BATCH] = -tot / (float)BATCH;
    }
}

extern "C" void kernel_launch(void* const* d_in, const int* in_sizes, int n_in,
                              void* d_out, int out_size, void* d_ws, size_t ws_size,
                              hipStream_t stream) {
    (void)in_sizes; (void)n_in; (void)out_size; (void)ws_size;
    const float* text = (const float*)d_in[0];
    const float* virt = (const float*)d_in[1];
    const float* gum = (const float*)d_in[2];
    const int* idxb = (const int*)d_in[3];
    const int* esrc = (const int*)d_in[4];
    const int* edst = (const int*)d_in[5];
    const int* label = (const int*)d_in[6];
    float* out = (float*)d_out;

    float* Vn = (float*)d_ws;                 // 3072 f32
    float* Ginv = Vn + K * D;                 // 64 f32
    float* M1 = Ginv + K * K;                 // 64 f32
    float* scores = M1 + K * K;               // 512 f32
    uint16_t* Vbf = (uint16_t*)(scores + BATCH);  // 16*384 bf16 = 12288 B

    hipLaunchKernelGGL(prep_kernel, dim3(1), dim3(64), 0, stream, virt, Vn, Ginv, M1, Vbf);
    hipLaunchKernelGGL(batch_kernel, dim3(BATCH), dim3(512), 0, stream, text, gum, idxb,
                       esrc, edst, (const __hip_bfloat16*)Vbf, M1, scores);
    hipLaunchKernelGGL(finalize_kernel, dim3(1), dim3(512), 0, stream, scores, label, out);
}